// Round 9
// baseline (459.851 us; speedup 1.0000x reference)
//
#include <hip/hip_runtime.h>
#include <hip/hip_bf16.h>
#include <cstdint>

#define B_SZ 1000
#define D_SZ 512
#define N_SZ 100000
#define F_SZ 50
#define NEGV -1000000.0f

// ---- 128x256 main tile geometry (2 blocks/CU) ----
#define BMr 128              // b-rows per tile
#define BNc 256              // n-cols per tile
#define NT_N3 391            // 391*256 = 100096
#define NT_B3 8              // 1024/128
#define G3 (NT_B3 * NT_N3)   // 3128 blocks (divisible by 8 XCDs)

#define T_OFF 0
#define FENT_OFF 4096            // fent: 1024*64*4B = 256 KB (ends < 2MB)
#define QB_OFF  0x200000         // qb3: 8*16*4*128*16B = 1 MB (2 MB region)
#define RT_OFF  0x400000         // rhsT3: 391*16*4*256*16B = 102.5 MB
#define RT_ROWS 100096
#define SENT 0xFFFFFFFFu

typedef __bf16 bf16x8 __attribute__((ext_vector_type(8)));
typedef float f32x4 __attribute__((ext_vector_type(4)));

__device__ __forceinline__ void gl_lds16(const void* g, void* l){
  __builtin_amdgcn_global_load_lds(
      (const __attribute__((address_space(1))) unsigned int*)g,
      (__attribute__((address_space(3))) unsigned int*)l, 16, 0, 0);
}

// ---------------- fused setup: t[b] + dedupe->fent + q->qb (tiled) ---------
// Block b (1000 blocks x 256 thr):
//   all 256 thr : t[b] = q[b].rhs[:,target[b]]  (f32 exact)
//   wave 0      : dedupe filter∪target -> fent[b][64] (SENT-padded, no
//                 atomics, no zeroing pass needed); out[b] init
//   wave 1      : convert q row b -> qb3 tiled bf16
//   block 0 w2/3: zero qb3 pad rows 1000..1023
// qb3 layout: [mt 8][kt 16][kq 4][row 128][8 bf16]
__global__ __launch_bounds__(256)
void setup_kernel(const float* __restrict__ q, const float* __restrict__ rhs,
                  const int* __restrict__ filt, const int* __restrict__ target,
                  float* __restrict__ t, unsigned* __restrict__ fent,
                  __bf16* __restrict__ qb, float* __restrict__ out){
  const int b = blockIdx.x;
  const int tid = threadIdx.x;
  __shared__ float red[4];
  __shared__ float tbs;
  const int tj = target[b];
  const float* qrow = q + (size_t)b * D_SZ;
  float p = qrow[tid] * rhs[(size_t)tid * N_SZ + tj]
          + qrow[tid + 256] * rhs[(size_t)(tid + 256) * N_SZ + tj];
  for(int off = 32; off; off >>= 1) p += __shfl_down(p, off);
  if((tid & 63) == 0) red[tid >> 6] = p;
  __syncthreads();
  if(tid == 0){ float tb = red[0] + red[1] + red[2] + red[3]; t[b] = tb; tbs = tb; }
  __syncthreads();

  if(tid < 64){
    // wave 0: shuffle-based first-occurrence dedupe (no scratch arrays)
    const int lane = tid;
    int v = 0x7fffffff;
    if(lane < F_SZ) v = filt[b * F_SZ + lane];
    else if(lane == F_SZ) v = tj;
    const bool active = lane <= F_SZ;
    bool first = active;
    #pragma unroll 1
    for(int k = 0; k < F_SZ; k++){
      int o = __shfl(v, k);
      if(active && k < lane && o == v) first = false;
    }
    fent[(size_t)b * 64 + lane] = first ? (unsigned)v : SENT;
    int nuniq = (int)__popcll(__ballot(first));
    if(lane == 0) out[b] = 1.0f + ((NEGV >= tbs) ? (float)nuniq : 0.0f);
  } else if(tid < 128){
    // wave 1: q row b -> qb3 (chunk c = 8 k's)
    const int c = tid - 64;            // 0..63, k0 = c*8
    float4 v0 = *(const float4*)(qrow + c * 8);
    float4 v1 = *(const float4*)(qrow + c * 8 + 4);
    bf16x8 w = { (__bf16)v0.x,(__bf16)v0.y,(__bf16)v0.z,(__bf16)v0.w,
                 (__bf16)v1.x,(__bf16)v1.y,(__bf16)v1.z,(__bf16)v1.w };
    const int mt = b >> 7, r = b & 127, kt = c >> 2, kq = c & 3;
    *(bf16x8*)(qb + ((size_t)(mt*16 + kt)*4 + kq) * 1024 + (size_t)r * 8) = w;
  } else if(b == 0){
    // block 0 waves 2-3: zero pad rows 1000..1023 (24 rows x 64 chunks)
    const bf16x8 z = { (__bf16)0.f,(__bf16)0.f,(__bf16)0.f,(__bf16)0.f,
                       (__bf16)0.f,(__bf16)0.f,(__bf16)0.f,(__bf16)0.f };
    for(int i = tid - 128; i < 1536; i += 128){
      int row = 1000 + (i >> 6), c = i & 63;
      int mt = row >> 7, r = row & 127, kt = c >> 2, kq = c & 3;
      *(bf16x8*)(qb + ((size_t)(mt*16 + kt)*4 + kq) * 1024 + (size_t)r * 8) = z;
    }
  }
}

// ---------------- rhs f32 [512][100000] -> rhsT3 tiled bf16 ----------------
// rhsT3 layout: [nt 391][kt 16][kq 4][row 256][8 bf16]
__global__ __launch_bounds__(256)
void tconv_kernel(const float* __restrict__ rhs, __bf16* __restrict__ rhsT){
  __shared__ float tile[64][65];
  const int tn = blockIdx.x;           // 0..1563
  const int tk = blockIdx.y;           // 0..7 (64 k's per block)
  const int tid = threadIdx.x;
  const int n0 = tn * 64, k0 = tk * 64;
  // read phase: coalesced along n
  {
    const int nc = (tid & 15) * 4;
    const int kr0 = tid >> 4;          // 0..15
    #pragma unroll
    for(int i = 0; i < 4; i++){
      int kr = kr0 + i * 16;
      int n = n0 + nc;
      float4 v = (n < N_SZ) ? *(const float4*)(rhs + (size_t)(k0 + kr) * N_SZ + n)
                            : make_float4(0.f,0.f,0.f,0.f);
      tile[kr][nc+0] = v.x; tile[kr][nc+1] = v.y;
      tile[kr][nc+2] = v.z; tile[kr][nc+3] = v.w;
    }
  }
  __syncthreads();
  // write phase: lane = n (coalesced 1KB per kq region)
  {
    const int nl = tid & 63;
    const int kc = (tid >> 6) * 16;    // 0,16,32,48
    float a[16];
    #pragma unroll
    for(int j = 0; j < 16; j++) a[j] = tile[kc + j][nl];
    bf16x8 w0, w1;
    #pragma unroll
    for(int j = 0; j < 8; j++){ w0[j] = (__bf16)a[j]; w1[j] = (__bf16)a[8 + j]; }
    const int ng = n0 + nl;
    const int nt = ng >> 8, r = ng & 255;
    const int kg = k0 + kc;            // multiple of 16
    const int kt = kg >> 5, kq0 = (kg >> 3) & 3;   // kq0 in {0,2}
    __bf16* dst = rhsT + ((size_t)(nt*16 + kt)*4 + kq0) * 2048 + (size_t)r * 8;
    *(bf16x8*)dst = w0;
    *(bf16x8*)(dst + 2048) = w1;       // kq0+1
  }
}

// ---------------- fused 128x256 MFMA GEMM + rank count ---------------------
// UNCHANGED from R8's measured-good loop (151 us, MfmaUtil 29%, no spill):
// 8 waves (2M x 4N), per-wave 64x64 C (acc[4][4] = 64 regs), BK=32, 16
// K-tiles, 2-barrier loop, counted vmcnt(3), ~55KB LDS -> 2 blocks/CU.
// ONLY the filter-table path changed: binned entries -> coalesced scan of
// per-b fent rows (no cnt/CAP, no zero_ws ordering dependency).
__global__ __launch_bounds__(512, 4)
void main_kernel(const __bf16* __restrict__ rhsT, const __bf16* __restrict__ qb,
                 const float* __restrict__ t, const unsigned* __restrict__ fent,
                 float* __restrict__ out){
  __shared__ __attribute__((aligned(16))) __bf16 A2[2][4096];  // 2x8 KB
  __shared__ __attribute__((aligned(16))) __bf16 B2[2][8192];  // 2x16 KB
  __shared__ float tl[128];
  __shared__ unsigned bm[1024];      // 128 rows x 256 cols bitmap (4 KB)
  __shared__ int rowc[128];

  // ---- XCD swizzle: nwg=3128=8*391. XCD x owns wg [x*391,(x+1)*391);
  // consecutive wg share tile_n (8 tile_b sharers adjacent on one XCD).
  const int h = blockIdx.x;
  const int wg = (h & 7) * 391 + (h >> 3);
  const int tile_n = wg >> 3;        // 0..390
  const int tile_b = wg & 7;         // 0..7
  const int tid = threadIdx.x;
  const int n0 = tile_n * BNc;
  const int b0 = tile_b * BMr;

  if(tid < 128){ int b = b0 + tid; tl[tid] = (b < B_SZ) ? t[b] : 0.f; rowc[tid] = 0; }
  if(tid < 512){ bm[tid] = 0; bm[tid + 512] = 0; }

  const int wave = tid >> 6, lane = tid & 63;
  const int quad = lane >> 4, l15 = lane & 15;
  const int wm = wave >> 2, wn = wave & 3;   // 2 x 4 wave grid

  // loop-invariant LDS frag indices (elements)
  const int idxA = quad * 1024 + (wm * 64 + l15) * 8;
  const int idxB = quad * 2048 + (wn * 64 + l15) * 8;

  // global staging pointers (linear: global layout == LDS layout)
  const __bf16* pAg = qb   + (size_t)tile_b * 65536  + (size_t)tid * 8;
  const __bf16* pBg = rhsT + (size_t)tile_n * 131072 + (size_t)tid * 8;

  f32x4 acc[4][4];
  #pragma unroll
  for(int i = 0; i < 4; i++)
    #pragma unroll
    for(int j = 0; j < 4; j++)
      acc[i][j] = (f32x4){0.f, 0.f, 0.f, 0.f};

  __syncthreads();                 // tl/bm writes visible
  // ---- mark filter bitmap: scan fent rows b0..b0+127 (8192 slots, 16/thr).
  // Unwritten rows (b>=1000, poisoned ws) and SENT slots fail d<256 check.
  {
    const unsigned* fb = fent + (size_t)b0 * 64;
    #pragma unroll
    for(int e = 0; e < 16; e++){
      unsigned v = fb[e * 512 + tid];
      unsigned d = v - (unsigned)n0;
      if(d < 256u){
        int bl = (e * 512 + tid) >> 6;       // local b row
        atomicOr(&bm[bl * 8 + (d >> 5)], 1u << (d & 31));
      }
    }
  }
  // ---- prologue: stage K-tile 0 into buffer 0 (3 loads/thread)
  gl_lds16(pAg,        &A2[0][tid * 8]);
  gl_lds16(pBg,        &B2[0][tid * 8]);
  gl_lds16(pBg + 4096, &B2[0][4096 + tid * 8]);
  pAg += 4096; pBg += 8192;
  asm volatile("s_waitcnt vmcnt(0)" ::: "memory");
  __builtin_amdgcn_s_barrier();
  asm volatile("" ::: "memory");

  #pragma unroll 1
  for(int kt = 0; kt < 16; kt++){
    const int cur = kt & 1, nxt = cur ^ 1;
    if(kt < 15){
      // issue next tile's 3 loads; vmcnt(3) drains only tile kt's loads
      gl_lds16(pAg,        &A2[nxt][tid * 8]);
      gl_lds16(pBg,        &B2[nxt][tid * 8]);
      gl_lds16(pBg + 4096, &B2[nxt][4096 + tid * 8]);
      pAg += 4096; pBg += 8192;
      asm volatile("s_waitcnt vmcnt(3)" ::: "memory");
    } else {
      asm volatile("s_waitcnt vmcnt(0)" ::: "memory");
    }
    __builtin_amdgcn_s_barrier();        // tile kt resident for all waves
    asm volatile("" ::: "memory");

    bf16x8 a4[4], b4[4];
    #pragma unroll
    for(int i = 0; i < 4; i++) a4[i] = *(const bf16x8*)&A2[cur][idxA + i * 128];
    #pragma unroll
    for(int j = 0; j < 4; j++) b4[j] = *(const bf16x8*)&B2[cur][idxB + j * 128];
    __builtin_amdgcn_s_setprio(1);
    #pragma unroll
    for(int i = 0; i < 4; i++)
      #pragma unroll
      for(int j = 0; j < 4; j++)
        acc[i][j] = __builtin_amdgcn_mfma_f32_16x16x32_bf16(a4[i], b4[j], acc[i][j], 0, 0, 0);
    __builtin_amdgcn_s_setprio(0);

    asm volatile("s_waitcnt lgkmcnt(0)" ::: "memory");  // reads of buf[cur] done
    __builtin_amdgcn_s_barrier();
    asm volatile("" ::: "memory");
  }

  // ---- epilogue: count s >= t_row, excluding bitmap-marked filter entries --
  // C/D layout: col = l15 (+16j), row = quad*4 + r (+16i) [verified mapping]
  #pragma unroll
  for(int i = 0; i < 4; i++){
    #pragma unroll
    for(int r = 0; r < 4; r++){
      const int row = wm*64 + i*16 + quad*4 + r;
      const float trow = tl[row];
      const unsigned w01 = bm[row * 8 + wn * 2];
      const unsigned w23 = bm[row * 8 + wn * 2 + 1];
      int c = 0;
      bool ge[4];
      #pragma unroll
      for(int j = 0; j < 4; j++){
        int ncol = n0 + wn*64 + j*16 + l15;
        ge[j] = (ncol < N_SZ) && (acc[i][j][r] >= trow);
        c += ge[j] ? 1 : 0;
      }
      if(w01 | w23){                      // rare
        #pragma unroll
        for(int j = 0; j < 4; j++){
          unsigned w = (j < 2) ? w01 : w23;
          if(((w >> ((j & 1) * 16 + l15)) & 1u) && ge[j]) c--;
        }
      }
      c += __shfl_xor(c, 1);
      c += __shfl_xor(c, 2);
      c += __shfl_xor(c, 4);
      c += __shfl_xor(c, 8);
      if(l15 == 0) atomicAdd(&rowc[row], c);
    }
  }
  __syncthreads();
  if(tid < 128){
    int bg = b0 + tid, c = rowc[tid];
    if(bg < B_SZ && c) atomicAdd(&out[bg], (float)c);
  }
}

// ---------------- small-ws fallback path -----------------------------------
__global__ void t_kernel(const float* __restrict__ q, const float* __restrict__ rhs,
                         const int* __restrict__ target, float* __restrict__ t){
  int b = blockIdx.x;
  int tid = threadIdx.x;
  int tj = target[b];
  const float* qb = q + (size_t)b * D_SZ;
  float p = qb[tid] * rhs[(size_t)tid * N_SZ + tj]
          + qb[tid + 256] * rhs[(size_t)(tid + 256) * N_SZ + tj];
  for(int off = 32; off; off >>= 1) p += __shfl_down(p, off);
  __shared__ float red[4];
  if((tid & 63) == 0) red[tid >> 6] = p;
  __syncthreads();
  if(tid == 0) t[b] = red[0] + red[1] + red[2] + red[3];
}

__global__ __launch_bounds__(64)
void prep_lite(const int* __restrict__ filt, const int* __restrict__ target,
               const float* __restrict__ t, float* __restrict__ out){
  const int b = blockIdx.x;
  const int lane = threadIdx.x;
  int v = 0x7fffffff;
  if(lane < F_SZ) v = filt[b * F_SZ + lane];
  else if(lane == F_SZ) v = target[b];
  const bool active = lane <= F_SZ;
  bool first = active;
  #pragma unroll 1
  for(int k = 0; k < F_SZ; k++){
    int o = __shfl(v, k);
    if(active && k < lane && o == v) first = false;
  }
  int nuniq = (int)__popcll(__ballot(first));
  if(lane == 0){
    float tb = t[b];
    out[b] = 1.0f + ((NEGV >= tb) ? (float)nuniq : 0.0f);
  }
}

__global__ __launch_bounds__(256)
void fallback_kernel(const float* __restrict__ q, const float* __restrict__ rhs,
                     const int* __restrict__ filt, const int* __restrict__ target,
                     const float* __restrict__ t, float* __restrict__ out){
  const int b = blockIdx.x;
  const int tid = threadIdx.x;
  __shared__ float qs[D_SZ];
  __shared__ int fs[F_SZ + 1];
  __shared__ float tbs;
  qs[tid] = q[(size_t)b * D_SZ + tid];
  qs[tid + 256] = q[(size_t)b * D_SZ + tid + 256];
  if(tid < F_SZ) fs[tid] = filt[b * F_SZ + tid];
  if(tid == F_SZ) fs[tid] = target[b];
  if(tid == 0) tbs = t[b];
  __syncthreads();
  const float tb = tbs;
  int c = 0;
  const int nend = (blockIdx.y + 1) * 2048 < N_SZ ? (blockIdx.y + 1) * 2048 : N_SZ;
  for(int n = blockIdx.y * 2048 + tid; n < nend; n += 256){
    float s = 0.f;
    for(int k = 0; k < D_SZ; k++) s += qs[k] * rhs[(size_t)k * N_SZ + n];
    if(s >= tb){
      bool m = false;
      for(int i = 0; i <= F_SZ; i++) if(fs[i] == n){ m = true; break; }
      if(!m) c++;
    }
  }
  for(int off = 32; off; off >>= 1) c += __shfl_down(c, off);
  __shared__ int red[4];
  if((tid & 63) == 0) red[tid >> 6] = c;
  __syncthreads();
  if(tid == 0){
    int s = red[0] + red[1] + red[2] + red[3];
    if(s) atomicAdd(&out[b], (float)s);
  }
}

extern "C" void kernel_launch(void* const* d_in, const int* in_sizes, int n_in,
                              void* d_out, int out_size, void* d_ws, size_t ws_size,
                              hipStream_t stream){
  const float* q    = (const float*)d_in[0];
  const float* rhs  = (const float*)d_in[1];
  const int* filt   = (const int*)d_in[2];
  const int* target = (const int*)d_in[3];
  float* out = (float*)d_out;
  char* ws = (char*)d_ws;
  float* t          = (float*)(ws + T_OFF);
  unsigned* fent    = (unsigned*)(ws + FENT_OFF);
  __bf16* qb        = (__bf16*)(ws + QB_OFF);
  __bf16* rhsT      = (__bf16*)(ws + RT_OFF);

  const size_t need = (size_t)RT_OFF + (size_t)RT_ROWS * D_SZ * 2;   // ~106.7 MB
  const bool big = ws_size >= need;

  if(big){
    // 3 dispatches total (was 6): setup -> tconv -> main
    setup_kernel<<<B_SZ, 256, 0, stream>>>(q, rhs, filt, target, t, fent, qb, out);
    tconv_kernel<<<dim3(RT_ROWS / 64, 8), 256, 0, stream>>>(rhs, rhsT);
    main_kernel<<<G3, 512, 0, stream>>>(rhsT, qb, t, fent, out);
  } else {
    t_kernel<<<B_SZ, 256, 0, stream>>>(q, rhs, target, t);
    prep_lite<<<B_SZ, 64, 0, stream>>>(filt, target, t, out);
    fallback_kernel<<<dim3(B_SZ, 49), 256, 0, stream>>>(q, rhs, filt, target, t, out);
  }
}